// Round 18
// baseline (327.920 us; speedup 1.0000x reference)
//
#include <hip/hip_runtime.h>
#include <math.h>
#include <stdint.h>

#define CIN  96
#define COUT 384
#define HH   56
#define WW   56
#define BB   32

#define MARGIN   2e-3f
#define CAP      32000u
#define WT32_OFF (256 * 1024)
#define WT64_OFF (2 * 1024 * 1024)
#define WT16_OFF (5 * 1024 * 1024)
#define POSB     8

#define HL2      331776          // halves per hi/lo plane of wt16 (24*12*9*128)
#define XSB      6336            // halves per xs buffer (4*3*66*8), hi plane only

typedef _Float16 half8 __attribute__((ext_vector_type(8)));
typedef float    f32x4 __attribute__((ext_vector_type(4)));

// prep_all: one dispatch. Every thread writes one wt64[r][co] (coalesced);
// threads < HL2/8 additionally write one 8-half wt16 fragment row (coalesced
// 16B hi + 16B lo). Thread 0 zeroes the flag counter.
__global__ void prep_all(const float* __restrict__ w, _Float16* __restrict__ wt16,
                         double* __restrict__ wt64, uint32_t* __restrict__ cnt) {
    int idx = blockIdx.x * blockDim.x + threadIdx.x;
    if (idx == 0) *cnt = 0u;
    if (idx < COUT * CIN * 9) {
        int r  = idx / COUT;
        int co = idx - r * COUT;
        double d = (double)w[(size_t)co * (CIN * 9) + r];
        wt64[(size_t)r * COUT + co] = d * fabs(d);
    }
    if (idx < HL2 / 8) {
        int row = idx;
        int c16 = row & 15;            // co & 15
        int rem = row >> 4;
        int khw = rem % 9;
        int rem2 = rem / 9;
        int kp  = rem2 % 12;           // ci >> 3
        int nb  = rem2 / 12;           // co >> 4
        int co  = nb * 16 + c16;
        half8 hv, lv;
        #pragma unroll
        for (int j = 0; j < 8; ++j) {
            int ci = kp * 8 + j;
            float wv = w[(size_t)co * (CIN * 9) + ci * 9 + khw];
            double d = (double)wv;
            float ef = (float)(d * fabs(d));
            _Float16 hi = (_Float16)ef;
            hv[j] = hi;
            lv[j] = (_Float16)(ef - (float)hi);
        }
        *(half8*)(wt16 + (size_t)row * 8) = hv;
        *(half8*)(wt16 + HL2 + (size_t)row * 8) = lv;
    }
}

// MFMA conv, pure fp16 x fp16 (fp32 acc), MARGIN=2e-3 (8 sigma) + fp64 fixup.
// 12-wave blocks, acc[4][2], direct pre_x float4 stores. Each block zeroes
// its OWN wta slice wta[b][:,h,:] at entry (stores drain under conv stalls;
// barrier-ordered before the winner scatter) -> no separate zero dispatch.
__global__ __launch_bounds__(768, 6)
void conv_mfma(const float* __restrict__ x, const _Float16* __restrict__ wt16,
               float* __restrict__ out, uint32_t* __restrict__ cnt,
               uint32_t* __restrict__ flags) {
    const int h   = blockIdx.x;
    const int b   = blockIdx.y;
    const int tid = threadIdx.x;
    const int l   = tid & 63;
    const int wg  = tid >> 6;          // 0..11
    const int g   = l >> 4;            // 0..3
    const int c   = l & 15;

    __shared__ char lds[37888];
    _Float16* xs  = (_Float16*)lds;                    // 2 x [4][3][66][8] (25344B)
    float4*   red = (float4*)(lds + 25344);            // [12][64] (12288B)
    int*      win = (int*)(lds + 25344 + 12288);       // [64] (256B)

    const size_t wta_off = (size_t)BB * COUT * HH * WW;

    // ---- zero this block's wta slice: wta[b][co][h][0..55] for all co ----
    {
        float4* wbase = (float4*)(out + wta_off + (size_t)b * COUT * 3136 + (size_t)h * 56);
        f32x4 z = {0.f, 0.f, 0.f, 0.f};
        #pragma unroll
        for (int k = 0; k < 7; ++k) {
            int id = tid + k * 768;        // 0..5375 = 384 co x 14 float4
            int co = id / 14;
            int j  = id - co * 14;
            *(f32x4*)((float*)wbase + (size_t)co * 3136 + j * 4) = z;
        }
    }

    f32x4 acc[4][2];
    #pragma unroll
    for (int mf = 0; mf < 4; ++mf)
        #pragma unroll
        for (int nf = 0; nf < 2; ++nf)
            #pragma unroll
            for (int q = 0; q < 4; ++q) acc[mf][nf][q] = 0.0f;

    const _Float16* pa0 = xs + (g * 198 + c) * 8;   // lane A-base (halves)

    auto stage = [&](int chunk) {
        _Float16* xsb = xs + (chunk & 1) * XSB;
        const int ci0 = chunk * 32;
        for (int idx = tid; idx < 4 * 198; idx += 768) {
            int cq  = idx / 198;           // 8-ci group 0..3
            int rem = idx - cq * 198;      // r*66 + col
            int r   = rem / 66;
            int col = rem - r * 66;
            int gh  = h + r - 1;
            int gw  = col - 1;
            half8 hv = {};
            if ((unsigned)gh < 56u && (unsigned)gw < 56u) {
                const float* px = x + (((size_t)b * CIN + (ci0 + cq * 8)) * HH + gh) * WW + gw;
                #pragma unroll
                for (int i = 0; i < 8; ++i) hv[i] = (_Float16)px[i * 3136];
            }
            *(half8*)(xsb + (size_t)(cq * 198 + rem) * 8) = hv;
        }
    };

    stage(0);
    __syncthreads();

    for (int chunk = 0; chunk < 3; ++chunk) {
        if (chunk < 2) stage(chunk + 1);   // other buffer; overlaps compute

        const _Float16* pax = pa0 + (chunk & 1) * XSB;
        const _Float16* pb0 = wt16 + (size_t)(((wg * 2 + 0) * 12 + chunk * 4 + g) * 9) * 128 + c * 8;
        const _Float16* pb1 = wt16 + (size_t)(((wg * 2 + 1) * 12 + chunk * 4 + g) * 9) * 128 + c * 8;

        #pragma unroll
        for (int khw = 0; khw < 9; ++khw) {
            const int kh = khw / 3;
            const int kw = khw - kh * 3;
            half8 B0 = *(const half8*)(pb0 + khw * 128);
            half8 B1 = *(const half8*)(pb1 + khw * 128);
            #pragma unroll
            for (int mf = 0; mf < 4; ++mf) {
                half8 Ah = *(const half8*)(pax + (kh * 66 + mf * 16 + kw) * 8);
                acc[mf][0] = __builtin_amdgcn_mfma_f32_16x16x32_f16(Ah, B0, acc[mf][0], 0, 0, 0);
                acc[mf][1] = __builtin_amdgcn_mfma_f32_16x16x32_f16(Ah, B1, acc[mf][1], 0, 0, 0);
            }
        }
        __syncthreads();
    }

    // ---- argmax stage 1: per-wave candidates (32 co each) ----
    #pragma unroll
    for (int mf = 0; mf < 4; ++mf) {
        #pragma unroll
        for (int q = 0; q < 4; ++q) {
            float best = acc[mf][0][q];
            int   bco  = wg * 32 + c;
            float sec  = -1e30f;
            {
                float v = acc[mf][1][q];
                if (v > best) { sec = best; best = v; bco = wg * 32 + 16 + c; }
                else sec = v;
            }
            #pragma unroll
            for (int off = 1; off <= 8; off <<= 1) {
                float ov = __shfl_xor(best, off, 64);
                int   oc = __shfl_xor(bco,  off, 64);
                float os = __shfl_xor(sec,  off, 64);
                if (ov > best || (ov == best && oc < bco)) {
                    sec = fmaxf(best, os);
                    best = ov; bco = oc;
                } else {
                    sec = fmaxf(sec, ov);
                }
            }
            if (c == 0) {
                int m = mf * 16 + g * 4 + q;
                red[wg * 64 + m] = make_float4(best, sec, __int_as_float(bco), 0.0f);
            }
        }
    }
    __syncthreads();
    // ---- stage 2: merge 12 wave-entries per m (co-order preserves ties) ----
    {
        const int m = tid >> 3;        // 0..95
        const int j = tid & 7;
        if (m < 64) {
            float4 a = red[j * 64 + m];
            float best = a.x, sec = a.y;
            int   bco  = __float_as_int(a.z);
            if (j < 4) {               // fold entry j+8 (strictly higher co block)
                float4 d = red[(j + 8) * 64 + m];
                if (d.x > best) {
                    sec = fmaxf(best, d.y);
                    best = d.x; bco = __float_as_int(d.z);
                } else {
                    sec = fmaxf(sec, d.x);
                }
            }
            #pragma unroll
            for (int off = 1; off <= 4; off <<= 1) {
                float ov = __shfl_xor(best, off, 64);
                int   oc = __shfl_xor(bco,  off, 64);
                float os = __shfl_xor(sec,  off, 64);
                if (ov > best || (ov == best && oc < bco)) {
                    sec = fmaxf(best, os);
                    best = ov; bco = oc;
                } else {
                    sec = fmaxf(sec, ov);
                }
            }
            if (j == 0 && m < 56) {
                win[m] = bco;
                if ((best - sec) < MARGIN) {
                    uint32_t k = atomicAdd(cnt, 1u);
                    if (k < CAP) flags[k] = (uint32_t)((b * 56 + h) * 56 + m);
                }
            }
        }
    }
    __syncthreads();

    // ---- wta: winners only (slice zeroed above; ordering via barriers) ----
    if (tid < 56) {
        int co_w = win[tid];
        out[wta_off + ((size_t)(b * COUT + co_w)) * 3136 + (size_t)h * 56 + tid] = 1.0f;
    }

    // ---- direct pre_x stores from accumulators (no LDS roundtrip) ----
    #pragma unroll
    for (int nf = 0; nf < 2; ++nf) {
        const int co = wg * 32 + nf * 16 + c;
        float* basep = out + ((size_t)(b * COUT + co)) * 3136 + (size_t)h * 56;
        #pragma unroll
        for (int mf = 0; mf < 4; ++mf) {
            const int m0 = mf * 16 + g * 4;
            if (m0 <= 52) {                  // m0..m0+3 all < 56; skips (mf==3,g==3)
                f32x4 v;
                #pragma unroll
                for (int q = 0; q < 4; ++q) v[q] = acc[mf][nf][q];
                *(f32x4*)(basep + m0) = v;
            }
        }
    }
}

// ---- tier-2 prep + conv (proven fp32 VALU path, writes wta fully) ----
__global__ void prep_tier2(const float* __restrict__ w, float* __restrict__ wt32,
                           double* __restrict__ wt64, uint32_t* __restrict__ cnt) {
    int idx = blockIdx.x * blockDim.x + threadIdx.x;
    if (idx == 0) *cnt = 0u;
    if (idx >= COUT * CIN * 9) return;
    int r  = idx / COUT;
    int co = idx - r * COUT;
    double d = (double)w[(size_t)co * (CIN * 9) + r];
    double e = d * fabs(d);
    wt64[(size_t)r * COUT + co] = e;
    wt32[(size_t)r * COUT + co] = (float)e;
}

__global__ __launch_bounds__(512, 2)
void conv_wta_f32(const float* __restrict__ x, const float* __restrict__ wt,
                  float* __restrict__ out, uint32_t* __restrict__ cnt,
                  uint32_t* __restrict__ flags) {
    const int h0  = blockIdx.x * 2;
    const int b   = blockIdx.y;
    const int tid = threadIdx.x;
    const int cg  = tid & 63;
    const int wg  = tid >> 6;
    const int co0 = cg * 6;
    const int ws0 = wg * 7;

    __shared__ float xs[32 * 4 * 58];
    __shared__ int   win[2][56];

    float acc[2][6][7];
    #pragma unroll
    for (int r = 0; r < 2; ++r)
        #pragma unroll
        for (int c = 0; c < 6; ++c)
            #pragma unroll
            for (int i = 0; i < 7; ++i) acc[r][c][i] = 0.0f;

    for (int chunk = 0; chunk < 3; ++chunk) {
        const int ci0 = chunk * 32;
        __syncthreads();
        for (int idx = tid; idx < 32 * 4 * 58; idx += 512) {
            int ci  = idx / 232;
            int rem = idx - ci * 232;
            int r   = rem / 58;
            int c   = rem - r * 58;
            int gh  = h0 + r - 1;
            int gw  = c - 1;
            float v = 0.0f;
            if ((unsigned)gh < 56u && (unsigned)gw < 56u)
                v = x[(((size_t)b * CIN + (ci0 + ci)) * HH + gh) * WW + gw];
            xs[idx] = v;
        }
        __syncthreads();
        for (int ci = 0; ci < 32; ++ci) {
            const int gci = ci0 + ci;
            #pragma unroll
            for (int kh = 0; kh < 3; ++kh) {
                float xa[9], xb[9];
                const float* xr0 = &xs[(ci * 4 + kh) * 58 + ws0];
                const float* xr1 = &xs[(ci * 4 + kh + 1) * 58 + ws0];
                #pragma unroll
                for (int j = 0; j < 9; ++j) { xa[j] = xr0[j]; xb[j] = xr1[j]; }
                #pragma unroll
                for (int kw = 0; kw < 3; ++kw) {
                    const float* p = wt + (size_t)((gci * 3 + kh) * 3 + kw) * COUT + co0;
                    float2 w01 = *(const float2*)(p);
                    float2 w23 = *(const float2*)(p + 2);
                    float2 w45 = *(const float2*)(p + 4);
                    float wd[6] = {w01.x, w01.y, w23.x, w23.y, w45.x, w45.y};
                    #pragma unroll
                    for (int c = 0; c < 6; ++c)
                        #pragma unroll
                        for (int i = 0; i < 7; ++i) {
                            acc[0][c][i] = fmaf(wd[c], xa[i + kw], acc[0][c][i]);
                            acc[1][c][i] = fmaf(wd[c], xb[i + kw], acc[1][c][i]);
                        }
                }
            }
        }
    }

    #pragma unroll
    for (int rr = 0; rr < 2; ++rr) {
        #pragma unroll
        for (int i = 0; i < 7; ++i) {
            float best = acc[rr][0][i];
            int   bco  = co0;
            float sec  = -1e30f;
            #pragma unroll
            for (int c = 1; c < 6; ++c) {
                float v = acc[rr][c][i];
                if (v > best) { sec = best; best = v; bco = co0 + c; }
                else if (v > sec) sec = v;
            }
            #pragma unroll
            for (int off = 32; off > 0; off >>= 1) {
                float ov = __shfl_xor(best, off, 64);
                int   oc = __shfl_xor(bco,  off, 64);
                float os = __shfl_xor(sec,  off, 64);
                if (ov > best || (ov == best && oc < bco)) {
                    sec = fmaxf(best, os);
                    best = ov; bco = oc;
                } else {
                    sec = fmaxf(sec, ov);
                }
            }
            if (cg == 0) {
                win[rr][ws0 + i] = bco;
                if ((best - sec) < MARGIN) {
                    uint32_t k = atomicAdd(cnt, 1u);
                    if (k < CAP) flags[k] = (uint32_t)((b * 56 + (h0 + rr)) * 56 + (ws0 + i));
                }
            }
        }
    }

    const size_t wta_off = (size_t)BB * COUT * HH * WW;
    float* ldsT = xs;
    __syncthreads();
    for (int k = 0; k < 8; ++k) {
        if ((cg >> 3) == k) {
            const int cr = (cg & 7) * 6;
            #pragma unroll
            for (int c = 0; c < 6; ++c)
                #pragma unroll
                for (int rr = 0; rr < 2; ++rr)
                    #pragma unroll
                    for (int i = 0; i < 7; ++i)
                        ldsT[(cr + c) * 113 + rr * 56 + ws0 + i] = acc[rr][c][i];
        }
        __syncthreads();
        for (int l = tid; l < 48 * 112; l += 512) {
            int co_r = l / 112;
            int rem  = l - co_r * 112;
            int rr   = rem / 56;
            int w    = rem - rr * 56;
            int co   = k * 48 + co_r;
            float v  = ldsT[co_r * 113 + rem];
            size_t o = ((size_t)(b * COUT + co)) * 3136 + (size_t)(h0 + rr) * 56 + w;
            out[o] = v;
            out[wta_off + o] = (co == win[rr][w]) ? 1.0f : 0.0f;
        }
        __syncthreads();
    }
}

// fp64 fixup: POSB=8 positions/block; x staged fp32 exact; fp64 accumulate.
__global__ __launch_bounds__(384)
void fixup_f64(const float* __restrict__ x, const double* __restrict__ wt64,
               float* __restrict__ out, const uint32_t* __restrict__ cnt,
               const uint32_t* __restrict__ flags) {
    __shared__ float  xp[POSB][CIN * 9];
    __shared__ double sv[POSB][COUT];
    __shared__ int winners[POSB];

    uint32_t n = *cnt;
    if (n > CAP) n = CAP;
    const int tid = threadIdx.x;
    const int wg  = tid >> 6;
    const int lane = tid & 63;
    const size_t wta_off = (size_t)BB * COUT * HH * WW;

    for (uint32_t base = blockIdx.x * POSB; base < n; base += gridDim.x * POSB) {
        int np = (int)(n - base) < POSB ? (int)(n - base) : POSB;
        __syncthreads();
        for (int idx = tid; idx < np * CIN * 9; idx += 384) {
            int p  = idx / (CIN * 9);
            int r  = idx - p * (CIN * 9);
            int ci = r / 9;
            int k  = r - ci * 9;
            int kh = k / 3, kw = k - kh * 3;
            uint32_t pos = flags[base + p];
            int w_ = pos % 56;
            int h_ = (pos / 56) % 56;
            int b_ = pos / 3136;
            int gh = h_ + kh - 1, gw = w_ + kw - 1;
            float v = 0.0f;
            if ((unsigned)gh < 56u && (unsigned)gw < 56u)
                v = x[(((size_t)b_ * CIN + ci) * HH + gh) * WW + gw];
            xp[p][r] = v;
        }
        __syncthreads();
        {
            const int co = tid;
            double a[POSB];
            #pragma unroll
            for (int p = 0; p < POSB; ++p) a[p] = 0.0;
            #pragma unroll 4
            for (int r = 0; r < CIN * 9; ++r) {
                double wd = wt64[(size_t)r * COUT + co];
                #pragma unroll
                for (int p = 0; p < POSB; ++p)
                    a[p] = fma(wd, (double)xp[p][r], a[p]);
            }
            #pragma unroll
            for (int p = 0; p < POSB; ++p) sv[p][co] = a[p];
        }
        __syncthreads();
        for (int p = wg; p < np; p += 6) {
            double best = sv[p][lane * 6];
            int bco = lane * 6;
            #pragma unroll
            for (int c = 1; c < 6; ++c) {
                double v2 = sv[p][lane * 6 + c];
                if (v2 > best) { best = v2; bco = lane * 6 + c; }
            }
            #pragma unroll
            for (int off = 32; off > 0; off >>= 1) {
                double ov = __shfl_xor(best, off, 64);
                int    oc = __shfl_xor(bco,  off, 64);
                if (ov > best || (ov == best && oc < bco)) { best = ov; bco = oc; }
            }
            if (lane == 0) winners[p] = bco;
        }
        __syncthreads();
        for (int idx = tid; idx < np * COUT; idx += 384) {
            int p  = idx / COUT;
            int co = idx - p * COUT;
            uint32_t pos = flags[base + p];
            int w_ = pos % 56;
            int h_ = (pos / 56) % 56;
            int b_ = pos / 3136;
            size_t o = (((size_t)b_ * COUT + co) * HH + h_) * WW + w_;
            out[o] = (float)sv[p][co];
            out[wta_off + o] = (co == winners[p]) ? 1.0f : 0.0f;
        }
        __syncthreads();
    }
}

// ---- tier-3: full fp64 fallback (round-1 proven) ----
__global__ __launch_bounds__(256, 2)
void conv_wta_f64(const float* __restrict__ x, const float* __restrict__ wraw,
                  float* __restrict__ out) {
    const int whalf = blockIdx.x;
    const int h     = blockIdx.y;
    const int b     = blockIdx.z;
    const int tid   = threadIdx.x;
    const int cg    = tid & 63;
    const int wg    = tid >> 6;
    const int co0   = cg * 6;
    const int wbase = whalf * 28 + wg * 7;

    __shared__ float xs[32 * 3 * 30];
    double acc[6][7];
    #pragma unroll
    for (int c = 0; c < 6; ++c)
        #pragma unroll
        for (int i = 0; i < 7; ++i) acc[c][i] = 0.0;

    for (int chunk = 0; chunk < 3; ++chunk) {
        const int ci0 = chunk * 32;
        __syncthreads();
        for (int idx = tid; idx < 32 * 3 * 30; idx += 256) {
            int ci = idx / 90, rem = idx - ci * 90;
            int r = rem / 30, c = rem - r * 30;
            int gh = h + r - 1, gw = whalf * 28 - 1 + c;
            float v = 0.0f;
            if ((unsigned)gh < 56u && (unsigned)gw < 56u)
                v = x[(((size_t)b * CIN + (ci0 + ci)) * HH + gh) * WW + gw];
            xs[idx] = v;
        }
        __syncthreads();
        for (int ci = 0; ci < 32; ++ci) {
            const int gci = ci0 + ci;
            #pragma unroll
            for (int kh = 0; kh < 3; ++kh) {
                double xd[9];
                #pragma unroll
                for (int j = 0; j < 9; ++j)
                    xd[j] = (double)xs[(ci * 3 + kh) * 30 + wg * 7 + j];
                #pragma unroll
                for (int kw = 0; kw < 3; ++kw) {
                    #pragma unroll
                    for (int c = 0; c < 6; ++c) {
                        double d = (double)wraw[(size_t)(co0 + c) * (CIN * 9) + gci * 9 + kh * 3 + kw];
                        double wd = d * fabs(d);
                        #pragma unroll
                        for (int i = 0; i < 7; ++i)
                            acc[c][i] = fma(wd, xd[i + kw], acc[c][i]);
                    }
                }
            }
        }
    }
    const size_t wta_off = (size_t)BB * COUT * HH * WW;
    #pragma unroll
    for (int i = 0; i < 7; ++i) {
        double best = acc[0][i];
        int bco = co0;
        #pragma unroll
        for (int c = 1; c < 6; ++c)
            if (acc[c][i] > best) { best = acc[c][i]; bco = co0 + c; }
        #pragma unroll
        for (int off = 32; off > 0; off >>= 1) {
            double ov = __shfl_xor(best, off, 64);
            int    oc = __shfl_xor(bco,  off, 64);
            if (ov > best || (ov == best && oc < bco)) { best = ov; bco = oc; }
        }
        const int w = wbase + i;
        #pragma unroll
        for (int c = 0; c < 6; ++c) {
            size_t o = (((size_t)b * COUT + (co0 + c)) * HH + h) * WW + w;
            out[o] = (float)acc[c][i];
            out[wta_off + o] = (co0 + c == bco) ? 1.0f : 0.0f;
        }
    }
}

extern "C" void kernel_launch(void* const* d_in, const int* in_sizes, int n_in,
                              void* d_out, int out_size, void* d_ws, size_t ws_size,
                              hipStream_t stream) {
    (void)in_sizes; (void)n_in; (void)out_size;
    const float* x = (const float*)d_in[0];
    const float* w = (const float*)d_in[1];
    float* out = (float*)d_out;

    const size_t need16 = (size_t)WT16_OFF + (size_t)2 * HL2 * sizeof(_Float16);
    const size_t need64 = (size_t)WT64_OFF + (size_t)COUT * CIN * 9 * sizeof(double);

    uint32_t* cnt   = (uint32_t*)d_ws;
    uint32_t* flags = (uint32_t*)((char*)d_ws + 256);
    float*    wt32  = (float*)((char*)d_ws + WT32_OFF);
    double*   wt64  = (double*)((char*)d_ws + WT64_OFF);
    _Float16* wt16  = (_Float16*)((char*)d_ws + WT16_OFF);

    if (ws_size >= need16) {
        prep_all<<<(COUT * CIN * 9 + 255) / 256, 256, 0, stream>>>(w, wt16, wt64, cnt);
        conv_mfma<<<dim3(56, 32), 768, 0, stream>>>(x, wt16, out, cnt, flags);
        fixup_f64<<<256, 384, 0, stream>>>(x, wt64, out, cnt, flags);
    } else if (ws_size >= need64) {
        prep_tier2<<<(COUT * CIN * 9 + 255) / 256, 256, 0, stream>>>(w, wt32, wt64, cnt);
        conv_wta_f32<<<dim3(28, 32), 512, 0, stream>>>(x, wt32, out, cnt, flags);
        fixup_f64<<<256, 384, 0, stream>>>(x, wt64, out, cnt, flags);
    } else {
        conv_wta_f64<<<dim3(2, 56, 32), 256, 0, stream>>>(x, w, out);
    }
}

// Round 19
// 295.056 us; speedup vs baseline: 1.1114x; 1.1114x over previous
//
#include <hip/hip_runtime.h>
#include <math.h>
#include <stdint.h>

#define CIN  96
#define COUT 384
#define HH   56
#define WW   56
#define BB   32

#define MARGIN   2e-3f
#define CAP      32000u
#define WT32_OFF (256 * 1024)
#define WT64_OFF (2 * 1024 * 1024)
#define WT16_OFF (5 * 1024 * 1024)
#define POSB     8

#define HL2      331776          // halves per hi/lo plane of wt16 (24*12*9*128)
#define XSB      6336            // halves per xs buffer (4*3*66*8), hi plane only

typedef _Float16 half8 __attribute__((ext_vector_type(8)));
typedef float    f32x4 __attribute__((ext_vector_type(4)));

// prep_wt16: one thread = one 8-half fragment row -> coalesced 16B stores.
// Also zeroes the flag counter.
__global__ void prep_wt16(const float* __restrict__ w, _Float16* __restrict__ wt16,
                          uint32_t* __restrict__ cnt) {
    int row = blockIdx.x * blockDim.x + threadIdx.x;   // 0..41471
    if (row == 0) *cnt = 0u;
    if (row >= HL2 / 8) return;
    int c16 = row & 15;            // co & 15
    int rem = row >> 4;
    int khw = rem % 9;
    int rem2 = rem / 9;
    int kp  = rem2 % 12;           // ci >> 3
    int nb  = rem2 / 12;           // co >> 4
    int co  = nb * 16 + c16;
    half8 hv, lv;
    #pragma unroll
    for (int j = 0; j < 8; ++j) {
        int ci = kp * 8 + j;
        float wv = w[(size_t)co * (CIN * 9) + ci * 9 + khw];
        double d = (double)wv;
        float ef = (float)(d * fabs(d));
        _Float16 hi = (_Float16)ef;
        hv[j] = hi;
        lv[j] = (_Float16)(ef - (float)hi);
    }
    *(half8*)(wt16 + (size_t)row * 8) = hv;
    *(half8*)(wt16 + HL2 + (size_t)row * 8) = lv;
}

// prep_wt64: coalesced wt64[r][co] stores for the fixup kernel.
__global__ void prep_wt64(const float* __restrict__ w, double* __restrict__ wt64) {
    int idx = blockIdx.x * blockDim.x + threadIdx.x;
    if (idx >= COUT * CIN * 9) return;
    int r  = idx / COUT;
    int co = idx - r * COUT;
    double d = (double)w[(size_t)co * (CIN * 9) + r];
    wt64[(size_t)r * COUT + co] = d * fabs(d);
}

// tier-2 prep: wt32 + wt64 + cnt (fp32 fallback path only).
__global__ void prep_tier2(const float* __restrict__ w, float* __restrict__ wt32,
                           double* __restrict__ wt64, uint32_t* __restrict__ cnt) {
    int idx = blockIdx.x * blockDim.x + threadIdx.x;
    if (idx == 0) *cnt = 0u;
    if (idx >= COUT * CIN * 9) return;
    int r  = idx / COUT;
    int co = idx - r * COUT;
    double d = (double)w[(size_t)co * (CIN * 9) + r];
    double e = d * fabs(d);
    wt64[(size_t)r * COUT + co] = e;
    wt32[(size_t)r * COUT + co] = (float)e;
}

// MFMA conv, pure fp16 x fp16 (fp32 acc), MARGIN=2e-3 (8 sigma) + fp64 fixup.
// 12-wave blocks, acc[4][2], direct pre_x float4 stores. wta plane is
// memset-to-zero outside the kernel (measured best: r16=296 vs r17 zero
// kernel=302 vs r18 folded-into-conv=328); only the 56 winner elements
// per (b,h) are written here.
__global__ __launch_bounds__(768, 6)
void conv_mfma(const float* __restrict__ x, const _Float16* __restrict__ wt16,
               float* __restrict__ out, uint32_t* __restrict__ cnt,
               uint32_t* __restrict__ flags) {
    const int h   = blockIdx.x;
    const int b   = blockIdx.y;
    const int tid = threadIdx.x;
    const int l   = tid & 63;
    const int wg  = tid >> 6;          // 0..11
    const int g   = l >> 4;            // 0..3
    const int c   = l & 15;

    __shared__ char lds[37888];
    _Float16* xs  = (_Float16*)lds;                    // 2 x [4][3][66][8] (25344B)
    float4*   red = (float4*)(lds + 25344);            // [12][64] (12288B)
    int*      win = (int*)(lds + 25344 + 12288);       // [64] (256B)

    f32x4 acc[4][2];
    #pragma unroll
    for (int mf = 0; mf < 4; ++mf)
        #pragma unroll
        for (int nf = 0; nf < 2; ++nf)
            #pragma unroll
            for (int q = 0; q < 4; ++q) acc[mf][nf][q] = 0.0f;

    const _Float16* pa0 = xs + (g * 198 + c) * 8;   // lane A-base (halves)

    auto stage = [&](int chunk) {
        _Float16* xsb = xs + (chunk & 1) * XSB;
        const int ci0 = chunk * 32;
        for (int idx = tid; idx < 4 * 198; idx += 768) {
            int cq  = idx / 198;           // 8-ci group 0..3
            int rem = idx - cq * 198;      // r*66 + col
            int r   = rem / 66;
            int col = rem - r * 66;
            int gh  = h + r - 1;
            int gw  = col - 1;
            half8 hv = {};
            if ((unsigned)gh < 56u && (unsigned)gw < 56u) {
                const float* px = x + (((size_t)b * CIN + (ci0 + cq * 8)) * HH + gh) * WW + gw;
                #pragma unroll
                for (int i = 0; i < 8; ++i) hv[i] = (_Float16)px[i * 3136];
            }
            *(half8*)(xsb + (size_t)(cq * 198 + rem) * 8) = hv;
        }
    };

    stage(0);
    __syncthreads();

    for (int chunk = 0; chunk < 3; ++chunk) {
        if (chunk < 2) stage(chunk + 1);   // other buffer; overlaps compute

        const _Float16* pax = pa0 + (chunk & 1) * XSB;
        const _Float16* pb0 = wt16 + (size_t)(((wg * 2 + 0) * 12 + chunk * 4 + g) * 9) * 128 + c * 8;
        const _Float16* pb1 = wt16 + (size_t)(((wg * 2 + 1) * 12 + chunk * 4 + g) * 9) * 128 + c * 8;

        #pragma unroll
        for (int khw = 0; khw < 9; ++khw) {
            const int kh = khw / 3;
            const int kw = khw - kh * 3;
            half8 B0 = *(const half8*)(pb0 + khw * 128);
            half8 B1 = *(const half8*)(pb1 + khw * 128);
            #pragma unroll
            for (int mf = 0; mf < 4; ++mf) {
                half8 Ah = *(const half8*)(pax + (kh * 66 + mf * 16 + kw) * 8);
                acc[mf][0] = __builtin_amdgcn_mfma_f32_16x16x32_f16(Ah, B0, acc[mf][0], 0, 0, 0);
                acc[mf][1] = __builtin_amdgcn_mfma_f32_16x16x32_f16(Ah, B1, acc[mf][1], 0, 0, 0);
            }
        }
        __syncthreads();
    }

    // ---- argmax stage 1: per-wave candidates (32 co each) ----
    #pragma unroll
    for (int mf = 0; mf < 4; ++mf) {
        #pragma unroll
        for (int q = 0; q < 4; ++q) {
            float best = acc[mf][0][q];
            int   bco  = wg * 32 + c;
            float sec  = -1e30f;
            {
                float v = acc[mf][1][q];
                if (v > best) { sec = best; best = v; bco = wg * 32 + 16 + c; }
                else sec = v;
            }
            #pragma unroll
            for (int off = 1; off <= 8; off <<= 1) {
                float ov = __shfl_xor(best, off, 64);
                int   oc = __shfl_xor(bco,  off, 64);
                float os = __shfl_xor(sec,  off, 64);
                if (ov > best || (ov == best && oc < bco)) {
                    sec = fmaxf(best, os);
                    best = ov; bco = oc;
                } else {
                    sec = fmaxf(sec, ov);
                }
            }
            if (c == 0) {
                int m = mf * 16 + g * 4 + q;
                red[wg * 64 + m] = make_float4(best, sec, __int_as_float(bco), 0.0f);
            }
        }
    }
    __syncthreads();
    // ---- stage 2: merge 12 wave-entries per m (co-order preserves ties) ----
    {
        const int m = tid >> 3;        // 0..95
        const int j = tid & 7;
        if (m < 64) {
            float4 a = red[j * 64 + m];
            float best = a.x, sec = a.y;
            int   bco  = __float_as_int(a.z);
            if (j < 4) {               // fold entry j+8 (strictly higher co block)
                float4 d = red[(j + 8) * 64 + m];
                if (d.x > best) {
                    sec = fmaxf(best, d.y);
                    best = d.x; bco = __float_as_int(d.z);
                } else {
                    sec = fmaxf(sec, d.x);
                }
            }
            #pragma unroll
            for (int off = 1; off <= 4; off <<= 1) {
                float ov = __shfl_xor(best, off, 64);
                int   oc = __shfl_xor(bco,  off, 64);
                float os = __shfl_xor(sec,  off, 64);
                if (ov > best || (ov == best && oc < bco)) {
                    sec = fmaxf(best, os);
                    best = ov; bco = oc;
                } else {
                    sec = fmaxf(sec, ov);
                }
            }
            if (j == 0 && m < 56) {
                win[m] = bco;
                if ((best - sec) < MARGIN) {
                    uint32_t k = atomicAdd(cnt, 1u);
                    if (k < CAP) flags[k] = (uint32_t)((b * 56 + h) * 56 + m);
                }
            }
        }
    }
    __syncthreads();

    const size_t wta_off = (size_t)BB * COUT * HH * WW;

    // ---- wta: winners only (plane is pre-zeroed) ----
    if (tid < 56) {
        int co_w = win[tid];
        out[wta_off + ((size_t)(b * COUT + co_w)) * 3136 + (size_t)h * 56 + tid] = 1.0f;
    }

    // ---- direct pre_x stores from accumulators (no LDS roundtrip) ----
    #pragma unroll
    for (int nf = 0; nf < 2; ++nf) {
        const int co = wg * 32 + nf * 16 + c;
        float* basep = out + ((size_t)(b * COUT + co)) * 3136 + (size_t)h * 56;
        #pragma unroll
        for (int mf = 0; mf < 4; ++mf) {
            const int m0 = mf * 16 + g * 4;
            if (m0 <= 52) {                  // m0..m0+3 all < 56; skips (mf==3,g==3)
                f32x4 v;
                #pragma unroll
                for (int q = 0; q < 4; ++q) v[q] = acc[mf][nf][q];
                *(f32x4*)(basep + m0) = v;
            }
        }
    }
}

// ---- tier-2: round-4 fp32 VALU conv (proven; writes wta fully, no memset) ----
__global__ __launch_bounds__(512, 2)
void conv_wta_f32(const float* __restrict__ x, const float* __restrict__ wt,
                  float* __restrict__ out, uint32_t* __restrict__ cnt,
                  uint32_t* __restrict__ flags) {
    const int h0  = blockIdx.x * 2;
    const int b   = blockIdx.y;
    const int tid = threadIdx.x;
    const int cg  = tid & 63;
    const int wg  = tid >> 6;
    const int co0 = cg * 6;
    const int ws0 = wg * 7;

    __shared__ float xs[32 * 4 * 58];
    __shared__ int   win[2][56];

    float acc[2][6][7];
    #pragma unroll
    for (int r = 0; r < 2; ++r)
        #pragma unroll
        for (int c = 0; c < 6; ++c)
            #pragma unroll
            for (int i = 0; i < 7; ++i) acc[r][c][i] = 0.0f;

    for (int chunk = 0; chunk < 3; ++chunk) {
        const int ci0 = chunk * 32;
        __syncthreads();
        for (int idx = tid; idx < 32 * 4 * 58; idx += 512) {
            int ci  = idx / 232;
            int rem = idx - ci * 232;
            int r   = rem / 58;
            int c   = rem - r * 58;
            int gh  = h0 + r - 1;
            int gw  = c - 1;
            float v = 0.0f;
            if ((unsigned)gh < 56u && (unsigned)gw < 56u)
                v = x[(((size_t)b * CIN + (ci0 + ci)) * HH + gh) * WW + gw];
            xs[idx] = v;
        }
        __syncthreads();
        for (int ci = 0; ci < 32; ++ci) {
            const int gci = ci0 + ci;
            #pragma unroll
            for (int kh = 0; kh < 3; ++kh) {
                float xa[9], xb[9];
                const float* xr0 = &xs[(ci * 4 + kh) * 58 + ws0];
                const float* xr1 = &xs[(ci * 4 + kh + 1) * 58 + ws0];
                #pragma unroll
                for (int j = 0; j < 9; ++j) { xa[j] = xr0[j]; xb[j] = xr1[j]; }
                #pragma unroll
                for (int kw = 0; kw < 3; ++kw) {
                    const float* p = wt + (size_t)((gci * 3 + kh) * 3 + kw) * COUT + co0;
                    float2 w01 = *(const float2*)(p);
                    float2 w23 = *(const float2*)(p + 2);
                    float2 w45 = *(const float2*)(p + 4);
                    float wd[6] = {w01.x, w01.y, w23.x, w23.y, w45.x, w45.y};
                    #pragma unroll
                    for (int c = 0; c < 6; ++c)
                        #pragma unroll
                        for (int i = 0; i < 7; ++i) {
                            acc[0][c][i] = fmaf(wd[c], xa[i + kw], acc[0][c][i]);
                            acc[1][c][i] = fmaf(wd[c], xb[i + kw], acc[1][c][i]);
                        }
                }
            }
        }
    }

    #pragma unroll
    for (int rr = 0; rr < 2; ++rr) {
        #pragma unroll
        for (int i = 0; i < 7; ++i) {
            float best = acc[rr][0][i];
            int   bco  = co0;
            float sec  = -1e30f;
            #pragma unroll
            for (int c = 1; c < 6; ++c) {
                float v = acc[rr][c][i];
                if (v > best) { sec = best; best = v; bco = co0 + c; }
                else if (v > sec) sec = v;
            }
            #pragma unroll
            for (int off = 32; off > 0; off >>= 1) {
                float ov = __shfl_xor(best, off, 64);
                int   oc = __shfl_xor(bco,  off, 64);
                float os = __shfl_xor(sec,  off, 64);
                if (ov > best || (ov == best && oc < bco)) {
                    sec = fmaxf(best, os);
                    best = ov; bco = oc;
                } else {
                    sec = fmaxf(sec, ov);
                }
            }
            if (cg == 0) {
                win[rr][ws0 + i] = bco;
                if ((best - sec) < MARGIN) {
                    uint32_t k = atomicAdd(cnt, 1u);
                    if (k < CAP) flags[k] = (uint32_t)((b * 56 + (h0 + rr)) * 56 + (ws0 + i));
                }
            }
        }
    }

    const size_t wta_off = (size_t)BB * COUT * HH * WW;
    float* ldsT = xs;
    __syncthreads();
    for (int k = 0; k < 8; ++k) {
        if ((cg >> 3) == k) {
            const int cr = (cg & 7) * 6;
            #pragma unroll
            for (int c = 0; c < 6; ++c)
                #pragma unroll
                for (int rr = 0; rr < 2; ++rr)
                    #pragma unroll
                    for (int i = 0; i < 7; ++i)
                        ldsT[(cr + c) * 113 + rr * 56 + ws0 + i] = acc[rr][c][i];
        }
        __syncthreads();
        for (int l = tid; l < 48 * 112; l += 512) {
            int co_r = l / 112;
            int rem  = l - co_r * 112;
            int rr   = rem / 56;
            int w    = rem - rr * 56;
            int co   = k * 48 + co_r;
            float v  = ldsT[co_r * 113 + rem];
            size_t o = ((size_t)(b * COUT + co)) * 3136 + (size_t)(h0 + rr) * 56 + w;
            out[o] = v;
            out[wta_off + o] = (co == win[rr][w]) ? 1.0f : 0.0f;
        }
        __syncthreads();
    }
}

// fp64 fixup: POSB=8 positions/block; x staged fp32 exact; fp64 accumulate.
__global__ __launch_bounds__(384)
void fixup_f64(const float* __restrict__ x, const double* __restrict__ wt64,
               float* __restrict__ out, const uint32_t* __restrict__ cnt,
               const uint32_t* __restrict__ flags) {
    __shared__ float  xp[POSB][CIN * 9];
    __shared__ double sv[POSB][COUT];
    __shared__ int winners[POSB];

    uint32_t n = *cnt;
    if (n > CAP) n = CAP;
    const int tid = threadIdx.x;
    const int wg  = tid >> 6;
    const int lane = tid & 63;
    const size_t wta_off = (size_t)BB * COUT * HH * WW;

    for (uint32_t base = blockIdx.x * POSB; base < n; base += gridDim.x * POSB) {
        int np = (int)(n - base) < POSB ? (int)(n - base) : POSB;
        __syncthreads();
        for (int idx = tid; idx < np * CIN * 9; idx += 384) {
            int p  = idx / (CIN * 9);
            int r  = idx - p * (CIN * 9);
            int ci = r / 9;
            int k  = r - ci * 9;
            int kh = k / 3, kw = k - kh * 3;
            uint32_t pos = flags[base + p];
            int w_ = pos % 56;
            int h_ = (pos / 56) % 56;
            int b_ = pos / 3136;
            int gh = h_ + kh - 1, gw = w_ + kw - 1;
            float v = 0.0f;
            if ((unsigned)gh < 56u && (unsigned)gw < 56u)
                v = x[(((size_t)b_ * CIN + ci) * HH + gh) * WW + gw];
            xp[p][r] = v;
        }
        __syncthreads();
        {
            const int co = tid;
            double a[POSB];
            #pragma unroll
            for (int p = 0; p < POSB; ++p) a[p] = 0.0;
            #pragma unroll 4
            for (int r = 0; r < CIN * 9; ++r) {
                double wd = wt64[(size_t)r * COUT + co];
                #pragma unroll
                for (int p = 0; p < POSB; ++p)
                    a[p] = fma(wd, (double)xp[p][r], a[p]);
            }
            #pragma unroll
            for (int p = 0; p < POSB; ++p) sv[p][co] = a[p];
        }
        __syncthreads();
        for (int p = wg; p < np; p += 6) {
            double best = sv[p][lane * 6];
            int bco = lane * 6;
            #pragma unroll
            for (int c = 1; c < 6; ++c) {
                double v2 = sv[p][lane * 6 + c];
                if (v2 > best) { best = v2; bco = lane * 6 + c; }
            }
            #pragma unroll
            for (int off = 32; off > 0; off >>= 1) {
                double ov = __shfl_xor(best, off, 64);
                int    oc = __shfl_xor(bco,  off, 64);
                if (ov > best || (ov == best && oc < bco)) { best = ov; bco = oc; }
            }
            if (lane == 0) winners[p] = bco;
        }
        __syncthreads();
        for (int idx = tid; idx < np * COUT; idx += 384) {
            int p  = idx / COUT;
            int co = idx - p * COUT;
            uint32_t pos = flags[base + p];
            int w_ = pos % 56;
            int h_ = (pos / 56) % 56;
            int b_ = pos / 3136;
            size_t o = (((size_t)b_ * COUT + co) * HH + h_) * WW + w_;
            out[o] = (float)sv[p][co];
            out[wta_off + o] = (co == winners[p]) ? 1.0f : 0.0f;
        }
        __syncthreads();
    }
}

// ---- tier-3: full fp64 fallback (round-1 proven) ----
__global__ __launch_bounds__(256, 2)
void conv_wta_f64(const float* __restrict__ x, const float* __restrict__ wraw,
                  float* __restrict__ out) {
    const int whalf = blockIdx.x;
    const int h     = blockIdx.y;
    const int b     = blockIdx.z;
    const int tid   = threadIdx.x;
    const int cg    = tid & 63;
    const int wg    = tid >> 6;
    const int co0   = cg * 6;
    const int wbase = whalf * 28 + wg * 7;

    __shared__ float xs[32 * 3 * 30];
    double acc[6][7];
    #pragma unroll
    for (int c = 0; c < 6; ++c)
        #pragma unroll
        for (int i = 0; i < 7; ++i) acc[c][i] = 0.0;

    for (int chunk = 0; chunk < 3; ++chunk) {
        const int ci0 = chunk * 32;
        __syncthreads();
        for (int idx = tid; idx < 32 * 3 * 30; idx += 256) {
            int ci = idx / 90, rem = idx - ci * 90;
            int r = rem / 30, c = rem - r * 30;
            int gh = h + r - 1, gw = whalf * 28 - 1 + c;
            float v = 0.0f;
            if ((unsigned)gh < 56u && (unsigned)gw < 56u)
                v = x[(((size_t)b * CIN + (ci0 + ci)) * HH + gh) * WW + gw];
            xs[idx] = v;
        }
        __syncthreads();
        for (int ci = 0; ci < 32; ++ci) {
            const int gci = ci0 + ci;
            #pragma unroll
            for (int kh = 0; kh < 3; ++kh) {
                double xd[9];
                #pragma unroll
                for (int j = 0; j < 9; ++j)
                    xd[j] = (double)xs[(ci * 3 + kh) * 30 + wg * 7 + j];
                #pragma unroll
                for (int kw = 0; kw < 3; ++kw) {
                    #pragma unroll
                    for (int c = 0; c < 6; ++c) {
                        double d = (double)wraw[(size_t)(co0 + c) * (CIN * 9) + gci * 9 + kh * 3 + kw];
                        double wd = d * fabs(d);
                        #pragma unroll
                        for (int i = 0; i < 7; ++i)
                            acc[c][i] = fma(wd, xd[i + kw], acc[c][i]);
                    }
                }
            }
        }
    }
    const size_t wta_off = (size_t)BB * COUT * HH * WW;
    #pragma unroll
    for (int i = 0; i < 7; ++i) {
        double best = acc[0][i];
        int bco = co0;
        #pragma unroll
        for (int c = 1; c < 6; ++c)
            if (acc[c][i] > best) { best = acc[c][i]; bco = co0 + c; }
        #pragma unroll
        for (int off = 32; off > 0; off >>= 1) {
            double ov = __shfl_xor(best, off, 64);
            int    oc = __shfl_xor(bco,  off, 64);
            if (ov > best || (ov == best && oc < bco)) { best = ov; bco = oc; }
        }
        const int w = wbase + i;
        #pragma unroll
        for (int c = 0; c < 6; ++c) {
            size_t o = (((size_t)b * COUT + (co0 + c)) * HH + h) * WW + w;
            out[o] = (float)acc[c][i];
            out[wta_off + o] = (co0 + c == bco) ? 1.0f : 0.0f;
        }
    }
}

extern "C" void kernel_launch(void* const* d_in, const int* in_sizes, int n_in,
                              void* d_out, int out_size, void* d_ws, size_t ws_size,
                              hipStream_t stream) {
    (void)in_sizes; (void)n_in; (void)out_size;
    const float* x = (const float*)d_in[0];
    const float* w = (const float*)d_in[1];
    float* out = (float*)d_out;

    const size_t need16 = (size_t)WT16_OFF + (size_t)2 * HL2 * sizeof(_Float16);
    const size_t need64 = (size_t)WT64_OFF + (size_t)COUT * CIN * 9 * sizeof(double);
    const size_t plane  = (size_t)BB * COUT * HH * WW;   // elements per plane

    uint32_t* cnt   = (uint32_t*)d_ws;
    uint32_t* flags = (uint32_t*)((char*)d_ws + 256);
    float*    wt32  = (float*)((char*)d_ws + WT32_OFF);
    double*   wt64  = (double*)((char*)d_ws + WT64_OFF);
    _Float16* wt16  = (_Float16*)((char*)d_ws + WT16_OFF);

    if (ws_size >= need16) {
        // zero the wta plane via memset node; conv writes winners only.
        // (r16=296us memset node; r17 custom zero kernel=302; r18 folded=328)
        hipMemsetAsync(out + plane, 0, plane * sizeof(float), stream);
        prep_wt16<<<(HL2 / 8 + 255) / 256, 256, 0, stream>>>(w, wt16, cnt);
        prep_wt64<<<(COUT * CIN * 9 + 255) / 256, 256, 0, stream>>>(w, wt64);
        conv_mfma<<<dim3(56, 32), 768, 0, stream>>>(x, wt16, out, cnt, flags);
        fixup_f64<<<256, 384, 0, stream>>>(x, wt64, out, cnt, flags);
    } else if (ws_size >= need64) {
        prep_tier2<<<(COUT * CIN * 9 + 255) / 256, 256, 0, stream>>>(w, wt32, wt64, cnt);
        conv_wta_f32<<<dim3(28, 32), 512, 0, stream>>>(x, wt32, out, cnt, flags);
        fixup_f64<<<256, 384, 0, stream>>>(x, wt64, out, cnt, flags);
    } else {
        conv_wta_f64<<<dim3(2, 56, 32), 256, 0, stream>>>(x, w, out);
    }
}